// Round 1
// baseline (316.652 us; speedup 1.0000x reference)
//
#include <hip/hip_runtime.h>
#include <math.h>

// Problem constants
#define BB    64
#define TT    512
#define TWOH  1024
#define TC    16                 // t-rows per chunk in k_scores_ct
#define NCHUNK (TT / TC)         // 32
#define NP_STRIDE ((TT + 1) * TWOH)  // 513*1024 = 525312

// -------------------------------------------------------------------------
// K1: q[b,e] = sum_d h[b,d] * W[d,e]
// grid = (4 e-chunks, 16 b-groups), block = 256. Each block: 4 b-rows x 256 e.
// W column reads are coalesced across threads; h reads are wave-uniform
// (scalar loads). Total W traffic 64 MiB, served from L2/L3 after first touch.
// -------------------------------------------------------------------------
__global__ __launch_bounds__(256) void k_qgemm(const float* __restrict__ h,
                                               const float* __restrict__ W,
                                               float* __restrict__ q) {
    const int e  = blockIdx.x * 256 + threadIdx.x;   // 0..1023
    const int b0 = blockIdx.y * 4;                   // 0..60
    const float* __restrict__ h0 = h + b0 * TWOH;
    const float* __restrict__ h1 = h0 + TWOH;
    const float* __restrict__ h2 = h1 + TWOH;
    const float* __restrict__ h3 = h2 + TWOH;
    float a0 = 0.f, a1 = 0.f, a2 = 0.f, a3 = 0.f;
    #pragma unroll 8
    for (int d = 0; d < TWOH; ++d) {
        const float w = W[d * TWOH + e];
        a0 = fmaf(h0[d], w, a0);
        a1 = fmaf(h1[d], w, a1);
        a2 = fmaf(h2[d], w, a2);
        a3 = fmaf(h3[d], w, a3);
    }
    q[(b0 + 0) * TWOH + e] = a0;
    q[(b0 + 1) * TWOH + e] = a1;
    q[(b0 + 2) * TWOH + e] = a2;
    q[(b0 + 3) * TWOH + e] = a3;
}

// -------------------------------------------------------------------------
// K2: per (b, t-chunk of 16):
//   - load prev[b,t,:] as float4 (register-resident), fused copy -> new_prev
//   - s[t] = q[b] . prev[b,t]  (wave shuffle-reduce + LDS combine of 4 waves)
//   - chunk-local online-softmax partial: m, l, ct_part = sum_t e^(s-m)*prev
//     (uses register-resident prev -- prev is read from HBM exactly once)
//   - write (m, l, ct_part[1024]) to workspace
// grid = (32 chunks, 64 b), block = 256 (thread tid owns d-slice [4tid,4tid+4))
// -------------------------------------------------------------------------
__global__ __launch_bounds__(256) void k_scores_ct(const float* __restrict__ prev,
                                                   const float* __restrict__ qg,
                                                   float* __restrict__ out_np,
                                                   float* __restrict__ ws_m,
                                                   float* __restrict__ ws_l,
                                                   float* __restrict__ ws_ct) {
    const int c   = blockIdx.x;          // chunk 0..31
    const int b   = blockIdx.y;          // 0..63
    const int t0  = c * TC;
    const int tid = threadIdx.x;         // 0..255
    const int lane = tid & 63;
    const int wid  = tid >> 6;

    __shared__ float s_part[TC][4];
    __shared__ float s_score[TC];

    const float4* __restrict__ prow =
        (const float4*)(prev + (size_t)b * TT * TWOH + (size_t)t0 * TWOH) + tid;
    float4* __restrict__ nprow =
        (float4*)(out_np + (size_t)b * NP_STRIDE + (size_t)t0 * TWOH) + tid;
    const float4 q4 = ((const float4*)(qg + b * TWOH))[tid];

    float4 pv[TC];
    #pragma unroll
    for (int t = 0; t < TC; ++t) {
        float4 v = prow[t * 256];
        pv[t] = v;
        nprow[t * 256] = v;                       // fused concat-copy
        float pd = v.x * q4.x + v.y * q4.y + v.z * q4.z + v.w * q4.w;
        #pragma unroll
        for (int off = 32; off > 0; off >>= 1)
            pd += __shfl_xor(pd, off, 64);
        if (lane == 0) s_part[t][wid] = pd;
    }
    __syncthreads();
    if (tid < TC)
        s_score[tid] = s_part[tid][0] + s_part[tid][1] + s_part[tid][2] + s_part[tid][3];
    __syncthreads();

    float m = -INFINITY;
    #pragma unroll
    for (int t = 0; t < TC; ++t) m = fmaxf(m, s_score[t]);
    float l = 0.f;
    float4 ct; ct.x = ct.y = ct.z = ct.w = 0.f;
    #pragma unroll
    for (int t = 0; t < TC; ++t) {
        const float w = __expf(s_score[t] - m);
        l += w;
        ct.x = fmaf(w, pv[t].x, ct.x);
        ct.y = fmaf(w, pv[t].y, ct.y);
        ct.z = fmaf(w, pv[t].z, ct.z);
        ct.w = fmaf(w, pv[t].w, ct.w);
    }
    ((float4*)(ws_ct + ((size_t)b * NCHUNK + c) * TWOH))[tid] = ct;
    if (tid == 0) {
        ws_m[b * NCHUNK + c] = m;
        ws_l[b * NCHUNK + c] = l;
    }
}

// -------------------------------------------------------------------------
// K3: combine 32 chunk partials per b:
//   M = max m_i; L = sum l_i * e^(m_i - M)
//   ct[b,d] = (sum_i e^(m_i - M) * ct_i[d]) / L
// Also writes the concat row: new_prev[b, 512, :] = h[b, :]
// grid = 64 (one per b), block = 256.
// -------------------------------------------------------------------------
__global__ __launch_bounds__(256) void k_finalize(const float* __restrict__ h,
                                                  const float* __restrict__ ws_m,
                                                  const float* __restrict__ ws_l,
                                                  const float* __restrict__ ws_ct,
                                                  float* __restrict__ out_ct,
                                                  float* __restrict__ out_np) {
    const int b   = blockIdx.x;
    const int tid = threadIdx.x;

    float M = -INFINITY;
    #pragma unroll
    for (int i = 0; i < NCHUNK; ++i) M = fmaxf(M, ws_m[b * NCHUNK + i]);

    float coef[NCHUNK];
    float L = 0.f;
    #pragma unroll
    for (int i = 0; i < NCHUNK; ++i) {
        const float e = __expf(ws_m[b * NCHUNK + i] - M);
        coef[i] = e;
        L = fmaf(e, ws_l[b * NCHUNK + i], L);
    }
    const float inv = 1.0f / L;

    float4 acc; acc.x = acc.y = acc.z = acc.w = 0.f;
    #pragma unroll
    for (int i = 0; i < NCHUNK; ++i) {
        const float4 v = ((const float4*)(ws_ct + ((size_t)b * NCHUNK + i) * TWOH))[tid];
        const float cc = coef[i];
        acc.x = fmaf(cc, v.x, acc.x);
        acc.y = fmaf(cc, v.y, acc.y);
        acc.z = fmaf(cc, v.z, acc.z);
        acc.w = fmaf(cc, v.w, acc.w);
    }
    acc.x *= inv; acc.y *= inv; acc.z *= inv; acc.w *= inv;
    ((float4*)(out_ct + b * TWOH))[tid] = acc;

    // concat row: new_prev[b, T, :] = h[b, :]
    const float4 hv = ((const float4*)(h + b * TWOH))[tid];
    ((float4*)(out_np + (size_t)b * NP_STRIDE + (size_t)TT * TWOH))[tid] = hv;
}

extern "C" void kernel_launch(void* const* d_in, const int* in_sizes, int n_in,
                              void* d_out, int out_size, void* d_ws, size_t ws_size,
                              hipStream_t stream) {
    const float* h    = (const float*)d_in[0];   // (64, 1024)
    const float* prev = (const float*)d_in[1];   // (64, 512, 1024)
    const float* W    = (const float*)d_in[2];   // (1, 1024, 1024)
    float* out    = (float*)d_out;
    float* out_ct = out;                         // (64, 1024)
    float* out_np = out + BB * TWOH;             // (64, 513, 1024)

    // workspace layout (floats): q[64*1024] | m[64*32] | l[64*32] | ct[64*32*1024]
    float* q   = (float*)d_ws;
    float* wsm = q + BB * TWOH;
    float* wsl = wsm + BB * NCHUNK;
    float* wsc = wsl + BB * NCHUNK;

    k_qgemm<<<dim3(4, 16), 256, 0, stream>>>(h, W, q);
    k_scores_ct<<<dim3(NCHUNK, BB), 256, 0, stream>>>(prev, q, out_np, wsm, wsl, wsc);
    k_finalize<<<BB, 256, 0, stream>>>(h, wsm, wsl, wsc, out_ct, out_np);
}

// Round 4
// 268.006 us; speedup vs baseline: 1.1815x; 1.1815x over previous
//
#include <hip/hip_runtime.h>
#include <math.h>

// Problem constants
#define BB    64
#define TT    512
#define TWOH  1024
#define TC    16                 // t-rows per chunk in k_scores_ct
#define NCHUNK (TT / TC)         // 32
#define KSPLIT 4                 // d-dim split for k_qgemm
#define NP_STRIDE ((TT + 1) * TWOH)  // 513*1024

// native clang vector type (vectorized loads/stores)
typedef float vfloat4 __attribute__((ext_vector_type(4)));

// NOTE (R3 post-mortem): __builtin_nontemporal_store on out_np caused
// post-timing divergence (poison landing after our stores under the
// harness's hipMemsetAsync re-poison) — do NOT use nt stores here.

// -------------------------------------------------------------------------
// K1: partial GEMM  qpart[k][b][e] = sum_{d in k-slice} h[b,d] * W[d,e]
// grid = (4 e-chunks, 64 b, 4 k-slices) = 1024 blocks -> 4 blocks/CU.
// h-slice staged in LDS; W reads coalesced, L2-resident after first touch.
// Partials summed by k_scores_ct's q-load.
// -------------------------------------------------------------------------
__global__ __launch_bounds__(256) void k_qgemm(const float* __restrict__ h,
                                               const float* __restrict__ W,
                                               float* __restrict__ qpart) {
    const int tid = threadIdx.x;
    const int e   = blockIdx.x * 256 + tid;      // 0..1023
    const int b   = blockIdx.y;                  // 0..63
    const int k   = blockIdx.z;                  // 0..3
    const int d0  = k * (TWOH / KSPLIT);         // 256-wide d slice

    __shared__ float sh[TWOH / KSPLIT];
    sh[tid] = h[b * TWOH + d0 + tid];
    __syncthreads();

    const float* __restrict__ Wp = W + (size_t)d0 * TWOH + e;
    float acc = 0.f;
    #pragma unroll 16
    for (int d = 0; d < TWOH / KSPLIT; ++d)
        acc = fmaf(sh[d], Wp[(size_t)d * TWOH], acc);

    qpart[((size_t)k * BB + b) * TWOH + e] = acc;
}

// -------------------------------------------------------------------------
// K2: per (b, t-chunk of 16):
//   - q[b] = sum of 4 k-partials (tiny, L2-hot)
//   - load prev[b,t,:] as float4 (register-resident), fused copy -> new_prev
//   - s[t] = q[b] . prev[b,t]  (wave shuffle-reduce + LDS combine of 4 waves)
//   - chunk-local online-softmax partial: m, l, ct_part = sum_t e^(s-m)*prev
//   - write (m, l, ct_part[1024]) to workspace
// grid = (32 chunks, 64 b), block = 256 (thread tid owns d-slice [4tid,4tid+4))
// -------------------------------------------------------------------------
__global__ __launch_bounds__(256) void k_scores_ct(const float* __restrict__ prev,
                                                   const float* __restrict__ qpart,
                                                   float* __restrict__ out_np,
                                                   float* __restrict__ ws_m,
                                                   float* __restrict__ ws_l,
                                                   float* __restrict__ ws_ct) {
    const int c   = blockIdx.x;          // chunk 0..31
    const int b   = blockIdx.y;          // 0..63
    const int t0  = c * TC;
    const int tid = threadIdx.x;         // 0..255
    const int lane = tid & 63;
    const int wid  = tid >> 6;

    __shared__ float s_part[TC][4];
    __shared__ float s_score[TC];

    const vfloat4* __restrict__ prow =
        (const vfloat4*)(prev + (size_t)b * TT * TWOH + (size_t)t0 * TWOH) + tid;
    vfloat4* __restrict__ nprow =
        (vfloat4*)(out_np + (size_t)b * NP_STRIDE + (size_t)t0 * TWOH) + tid;

    // q[b] slice = sum of 4 k-partials
    const vfloat4* __restrict__ qp = (const vfloat4*)qpart;
    vfloat4 q4 = qp[((size_t)0 * BB + b) * 256 + tid]
               + qp[((size_t)1 * BB + b) * 256 + tid]
               + qp[((size_t)2 * BB + b) * 256 + tid]
               + qp[((size_t)3 * BB + b) * 256 + tid];

    vfloat4 pv[TC];
    #pragma unroll
    for (int t = 0; t < TC; ++t) {
        vfloat4 v = prow[t * 256];
        pv[t] = v;
        nprow[t * 256] = v;                       // fused concat-copy (plain store)
        float pd = v.x * q4.x + v.y * q4.y + v.z * q4.z + v.w * q4.w;
        #pragma unroll
        for (int off = 32; off > 0; off >>= 1)
            pd += __shfl_xor(pd, off, 64);
        if (lane == 0) s_part[t][wid] = pd;
    }
    __syncthreads();
    if (tid < TC)
        s_score[tid] = s_part[tid][0] + s_part[tid][1] + s_part[tid][2] + s_part[tid][3];
    __syncthreads();

    float m = -INFINITY;
    #pragma unroll
    for (int t = 0; t < TC; ++t) m = fmaxf(m, s_score[t]);
    float l = 0.f;
    vfloat4 ct = (vfloat4)(0.f);
    #pragma unroll
    for (int t = 0; t < TC; ++t) {
        const float w = __expf(s_score[t] - m);
        l += w;
        ct.x = fmaf(w, pv[t].x, ct.x);
        ct.y = fmaf(w, pv[t].y, ct.y);
        ct.z = fmaf(w, pv[t].z, ct.z);
        ct.w = fmaf(w, pv[t].w, ct.w);
    }
    ((vfloat4*)(ws_ct + ((size_t)b * NCHUNK + c) * TWOH))[tid] = ct;
    if (tid == 0) {
        ws_m[b * NCHUNK + c] = m;
        ws_l[b * NCHUNK + c] = l;
    }
}

// -------------------------------------------------------------------------
// K3: combine 32 chunk partials per b:
//   M = max m_i; L = sum l_i * e^(m_i - M)
//   ct[b,e] = (sum_i e^(m_i - M) * ct_i[e]) / L
// Also writes the concat row: new_prev[b, 512, :] = h[b, :]
// grid = (4 e-chunks, 64 b) = 256 blocks; thread owns one e.
// -------------------------------------------------------------------------
__global__ __launch_bounds__(256) void k_finalize(const float* __restrict__ h,
                                                  const float* __restrict__ ws_m,
                                                  const float* __restrict__ ws_l,
                                                  const float* __restrict__ ws_ct,
                                                  float* __restrict__ out_ct,
                                                  float* __restrict__ out_np) {
    const int tid = threadIdx.x;
    const int e   = blockIdx.x * 256 + tid;
    const int b   = blockIdx.y;

    float M = -INFINITY;
    #pragma unroll
    for (int i = 0; i < NCHUNK; ++i) M = fmaxf(M, ws_m[b * NCHUNK + i]);

    float coef[NCHUNK];
    float L = 0.f;
    #pragma unroll
    for (int i = 0; i < NCHUNK; ++i) {
        const float ce = __expf(ws_m[b * NCHUNK + i] - M);
        coef[i] = ce;
        L = fmaf(ce, ws_l[b * NCHUNK + i], L);
    }
    const float inv = 1.0f / L;

    const float* __restrict__ cp = ws_ct + (size_t)b * NCHUNK * TWOH + e;
    float acc = 0.f;
    #pragma unroll
    for (int i = 0; i < NCHUNK; ++i)
        acc = fmaf(coef[i], cp[(size_t)i * TWOH], acc);
    out_ct[b * TWOH + e] = acc * inv;

    // concat row: new_prev[b, T, :] = h[b, :]
    out_np[(size_t)b * NP_STRIDE + (size_t)TT * TWOH + e] = h[b * TWOH + e];
}

extern "C" void kernel_launch(void* const* d_in, const int* in_sizes, int n_in,
                              void* d_out, int out_size, void* d_ws, size_t ws_size,
                              hipStream_t stream) {
    const float* h    = (const float*)d_in[0];   // (64, 1024)
    const float* prev = (const float*)d_in[1];   // (64, 512, 1024)
    const float* W    = (const float*)d_in[2];   // (1, 1024, 1024)
    float* out    = (float*)d_out;
    float* out_ct = out;                         // (64, 1024)
    float* out_np = out + BB * TWOH;             // (64, 513, 1024)

    // ws layout (floats): qpart[4*64*1024] | m[64*32] | l[64*32] | ct[64*32*1024]
    float* qpart = (float*)d_ws;
    float* wsm   = qpart + KSPLIT * BB * TWOH;
    float* wsl   = wsm + BB * NCHUNK;
    float* wsc   = wsl + BB * NCHUNK;

    k_qgemm<<<dim3(4, BB, KSPLIT), 256, 0, stream>>>(h, W, qpart);
    k_scores_ct<<<dim3(NCHUNK, BB), 256, 0, stream>>>(prev, qpart, out_np, wsm, wsl, wsc);
    k_finalize<<<dim3(4, BB), 256, 0, stream>>>(h, wsm, wsl, wsc, out_ct, out_np);
}

// Round 5
// 267.144 us; speedup vs baseline: 1.1853x; 1.0032x over previous
//
#include <hip/hip_runtime.h>
#include <math.h>

// Problem constants
#define BB    64
#define TT    512
#define TWOH  1024
#define TC    16                 // t-rows per chunk in k_scores_ct
#define NCHUNK (TT / TC)         // 32
#define KSPLIT 4                 // d-dim split for k_qgemm
#define NP_STRIDE ((TT + 1) * TWOH)  // 513*1024

// native clang vector type (vectorized loads/stores)
typedef float vfloat4 __attribute__((ext_vector_type(4)));

// NOTE (R3 post-mortem): __builtin_nontemporal_store on out_np caused
// post-timing divergence under the harness's re-poison path — no nt stores.

// -------------------------------------------------------------------------
// K1: partial GEMM  qpart[k][b][e] = sum_{d in k-slice} h[b,d] * W[d,e]
// grid = (4 e-chunks, 64 b, 4 k-slices) = 1024 blocks -> 4 blocks/CU.
// -------------------------------------------------------------------------
__global__ __launch_bounds__(256) void k_qgemm(const float* __restrict__ h,
                                               const float* __restrict__ W,
                                               float* __restrict__ qpart) {
    const int tid = threadIdx.x;
    const int e   = blockIdx.x * 256 + tid;      // 0..1023
    const int b   = blockIdx.y;                  // 0..63
    const int k   = blockIdx.z;                  // 0..3
    const int d0  = k * (TWOH / KSPLIT);         // 256-wide d slice

    __shared__ float sh[TWOH / KSPLIT];
    sh[tid] = h[b * TWOH + d0 + tid];
    __syncthreads();

    const float* __restrict__ Wp = W + (size_t)d0 * TWOH + e;
    float acc = 0.f;
    #pragma unroll 16
    for (int d = 0; d < TWOH / KSPLIT; ++d)
        acc = fmaf(sh[d], Wp[(size_t)d * TWOH], acc);

    qpart[((size_t)k * BB + b) * TWOH + e] = acc;
}

// -------------------------------------------------------------------------
// K2: per (b, t-chunk of 16):
//   Phase 1: ALL 16 prev-row float4 loads issued back-to-back (MLP).
//   Phase 2: dot-product partials + wave shuffle-reduce -> LDS.
//   Phase 3: barriers + chunk-local online-softmax partial (m, l, ct_part).
//   Phase 4: fused concat-copy stores to new_prev LAST (after final barrier,
//            so no __syncthreads vmcnt(0) drain waits on store completion).
// __launch_bounds__(256,4): VGPR ceiling 128 so pv[16] (64 VGPRs) stays
// register-resident — R4's 48-VGPR schedule serialized the loads (2.5 TB/s).
// grid = (32 chunks, 64 b), block = 256 (thread tid owns e-slice [4tid,4tid+4))
// -------------------------------------------------------------------------
__global__ __launch_bounds__(256, 4) void k_scores_ct(const float* __restrict__ prev,
                                                      const float* __restrict__ qpart,
                                                      float* __restrict__ out_np,
                                                      float* __restrict__ ws_m,
                                                      float* __restrict__ ws_l,
                                                      float* __restrict__ ws_ct) {
    const int c   = blockIdx.x;          // chunk 0..31
    const int b   = blockIdx.y;          // 0..63
    const int t0  = c * TC;
    const int tid = threadIdx.x;         // 0..255
    const int lane = tid & 63;
    const int wid  = tid >> 6;

    __shared__ float s_part[TC][4];
    __shared__ float s_score[TC];

    const vfloat4* __restrict__ prow =
        (const vfloat4*)(prev + (size_t)b * TT * TWOH + (size_t)t0 * TWOH) + tid;
    vfloat4* __restrict__ nprow =
        (vfloat4*)(out_np + (size_t)b * NP_STRIDE + (size_t)t0 * TWOH) + tid;

    // q[b] slice = sum of 4 k-partials (L2-hot)
    const vfloat4* __restrict__ qp = (const vfloat4*)qpart;
    vfloat4 q4 = qp[((size_t)0 * BB + b) * 256 + tid]
               + qp[((size_t)1 * BB + b) * 256 + tid]
               + qp[((size_t)2 * BB + b) * 256 + tid]
               + qp[((size_t)3 * BB + b) * 256 + tid];

    // Phase 1: batch all loads (16 in flight per thread)
    vfloat4 pv[TC];
    #pragma unroll
    for (int t = 0; t < TC; ++t)
        pv[t] = prow[t * 256];

    // Phase 2: dot partials + wave reduce
    #pragma unroll
    for (int t = 0; t < TC; ++t) {
        float pd = pv[t].x * q4.x + pv[t].y * q4.y + pv[t].z * q4.z + pv[t].w * q4.w;
        #pragma unroll
        for (int off = 32; off > 0; off >>= 1)
            pd += __shfl_xor(pd, off, 64);
        if (lane == 0) s_part[t][wid] = pd;
    }
    __syncthreads();
    if (tid < TC)
        s_score[tid] = s_part[tid][0] + s_part[tid][1] + s_part[tid][2] + s_part[tid][3];
    __syncthreads();

    // Phase 3: chunk-local online-softmax partial
    float m = -INFINITY;
    #pragma unroll
    for (int t = 0; t < TC; ++t) m = fmaxf(m, s_score[t]);
    float l = 0.f;
    vfloat4 ct = (vfloat4)(0.f);
    #pragma unroll
    for (int t = 0; t < TC; ++t) {
        const float w = __expf(s_score[t] - m);
        l += w;
        ct.x = fmaf(w, pv[t].x, ct.x);
        ct.y = fmaf(w, pv[t].y, ct.y);
        ct.z = fmaf(w, pv[t].z, ct.z);
        ct.w = fmaf(w, pv[t].w, ct.w);
    }
    ((vfloat4*)(ws_ct + ((size_t)b * NCHUNK + c) * TWOH))[tid] = ct;
    if (tid == 0) {
        ws_m[b * NCHUNK + c] = m;
        ws_l[b * NCHUNK + c] = l;
    }

    // Phase 4: fused concat-copy, issued last (no barrier after -> kernel-end drain)
    #pragma unroll
    for (int t = 0; t < TC; ++t)
        nprow[t * 256] = pv[t];
}

// -------------------------------------------------------------------------
// K3: combine 32 chunk partials per b; also new_prev[b,512,:] = h[b,:].
// grid = (4 e-chunks, 64 b) = 256 blocks; thread owns one e.
// -------------------------------------------------------------------------
__global__ __launch_bounds__(256) void k_finalize(const float* __restrict__ h,
                                                  const float* __restrict__ ws_m,
                                                  const float* __restrict__ ws_l,
                                                  const float* __restrict__ ws_ct,
                                                  float* __restrict__ out_ct,
                                                  float* __restrict__ out_np) {
    const int tid = threadIdx.x;
    const int e   = blockIdx.x * 256 + tid;
    const int b   = blockIdx.y;

    float M = -INFINITY;
    #pragma unroll
    for (int i = 0; i < NCHUNK; ++i) M = fmaxf(M, ws_m[b * NCHUNK + i]);

    float coef[NCHUNK];
    float L = 0.f;
    #pragma unroll
    for (int i = 0; i < NCHUNK; ++i) {
        const float ce = __expf(ws_m[b * NCHUNK + i] - M);
        coef[i] = ce;
        L = fmaf(ce, ws_l[b * NCHUNK + i], L);
    }
    const float inv = 1.0f / L;

    const float* __restrict__ cp = ws_ct + (size_t)b * NCHUNK * TWOH + e;
    float acc = 0.f;
    #pragma unroll
    for (int i = 0; i < NCHUNK; ++i)
        acc = fmaf(coef[i], cp[(size_t)i * TWOH], acc);
    out_ct[b * TWOH + e] = acc * inv;

    // concat row: new_prev[b, T, :] = h[b, :]
    out_np[(size_t)b * NP_STRIDE + (size_t)TT * TWOH + e] = h[b * TWOH + e];
}

extern "C" void kernel_launch(void* const* d_in, const int* in_sizes, int n_in,
                              void* d_out, int out_size, void* d_ws, size_t ws_size,
                              hipStream_t stream) {
    const float* h    = (const float*)d_in[0];   // (64, 1024)
    const float* prev = (const float*)d_in[1];   // (64, 512, 1024)
    const float* W    = (const float*)d_in[2];   // (1, 1024, 1024)
    float* out    = (float*)d_out;
    float* out_ct = out;                         // (64, 1024)
    float* out_np = out + BB * TWOH;             // (64, 513, 1024)

    // ws layout (floats): qpart[4*64*1024] | m[64*32] | l[64*32] | ct[64*32*1024]
    float* qpart = (float*)d_ws;
    float* wsm   = qpart + KSPLIT * BB * TWOH;
    float* wsl   = wsm + BB * NCHUNK;
    float* wsc   = wsl + BB * NCHUNK;

    k_qgemm<<<dim3(4, BB, KSPLIT), 256, 0, stream>>>(h, W, qpart);
    k_scores_ct<<<dim3(NCHUNK, BB), 256, 0, stream>>>(prev, qpart, out_np, wsm, wsl, wsc);
    k_finalize<<<dim3(4, BB), 256, 0, stream>>>(h, wsm, wsl, wsc, out_ct, out_np);
}